// Round 8
// baseline (102.585 us; speedup 1.0000x reference)
//
#include <hip/hip_runtime.h>
#include <hip/hip_bf16.h>
#include <cstdint>

using f32x4  = __attribute__((ext_vector_type(4))) float;
using bf16x8 = __attribute__((ext_vector_type(8))) short;
typedef unsigned short u16;

#define B_DIM 64
#define N_DIM 1024
#define P_DIM 256
#define NTILE 8              // N / 128
#define NUPPER 36            // NTILE*(NTILE+1)/2
#define NB_PREP 16384        // (B*N)/4
#define NB_GRAM 9216         // B * NUPPER * 4 wave-tasks (divisible by 8)
#define BK 32                // K-step: 8 steps over P=256

// RNE float->bf16
__device__ __forceinline__ u16 f2bf(float f) {
  uint32_t u = __float_as_uint(f);
  u += 0x7fffu + ((u >> 16) & 1u);
  return (u16)(u >> 16);
}

// ---------------------------------------------------------------------------
// Kernel 1: fused BCE partial + per-row sumsq + fp32->bf16 cast. (~HBM floor)
// ---------------------------------------------------------------------------
__global__ __launch_bounds__(256) void prep_kernel(
    const float* __restrict__ X, const float* __restrict__ T,
    u16* __restrict__ Xbf, float* __restrict__ sq,
    float* __restrict__ pb) {
  int tid  = threadIdx.x;
  int w    = tid >> 6, lane = tid & 63;
  size_t row = (size_t)blockIdx.x * 4 + w;
  const float4 xv = ((const float4*)(X + row * P_DIM))[lane];
  const float4 tv = ((const float4*)(T + row * P_DIM))[lane];
  float xs[4] = {xv.x, xv.y, xv.z, xv.w};
  float ts[4] = {tv.x, tv.y, tv.z, tv.w};
  float sqp = 0.f, bce = 0.f;
  ushort4 us;
  u16* up = (u16*)&us;
  #pragma unroll
  for (int i = 0; i < 4; ++i) {
    float x = xs[i];
    sqp += x * x;
    bce += fmaxf(x, 0.f) - x * ts[i] + __logf(1.f + __expf(-fabsf(x)));
    up[i] = f2bf(x);
  }
  ((ushort4*)(Xbf + row * P_DIM))[lane] = us;
  #pragma unroll
  for (int off = 32; off; off >>= 1) {
    sqp += __shfl_down(sqp, off);
    bce += __shfl_down(bce, off);
  }
  __shared__ float red[4];
  if (lane == 0) { sq[row] = sqp; red[w] = bce; }
  __syncthreads();
  if (tid == 0)
    pb[blockIdx.x] = red[0] + red[1] + red[2] + red[3];
}

// ---------------------------------------------------------------------------
// Kernel 2 (R8): wave-private decoupled Gram. One 64-thread block = one wave
// = one 64x64 output tile of one (b, TI, TJ) pair. The wave stages its OWN
// A/B 64x32 K-slabs into PRIVATE LDS (double-buffered, 16 KB/block -> 10
// blocks/CU, no other block coupling). ZERO __syncthreads: all load->write->
// read chains are wave-local; compiler's counted vmcnt/lgkmcnt forms the
// pipeline; named-reg reuse bounds prefetch depth to 1 step.
// Kept (counter-verified): XOR chunk swizzle (0 conflicts both LDS sides),
// monotone 64B-segment coalesced loads, XCD swizzle, diag dead-wave skip.
// ---------------------------------------------------------------------------
__global__ __launch_bounds__(64) void gram_kernel(
    const u16* __restrict__ Xbf, const float* __restrict__ sq,
    float* __restrict__ pd) {
  // [buf][mat A=0/B=1][64 rows * 32 u16] -> exactly 16 KB
  __shared__ __align__(16) u16 lds[2][2][64 * 32];

  // XCD-aware swizzle (NB_GRAM % 8 == 0): XCD x gets 1152 consecutive
  // logical ids = 8 batches (4 MB panel set = one L2).
  int p   = blockIdx.x;
  int gid = (p & 7) * (NB_GRAM / 8) + (p >> 3);
  int b   = gid / (NUPPER * 4);
  int r   = gid - b * (NUPPER * 4);
  int pr  = r >> 2;                     // tile-pair 0..35
  int wv  = r & 3;                      // wave slot within pair
  int TI  = 0, t = pr;
  while (t >= NTILE - TI) { t -= NTILE - TI; ++TI; }
  int TJ = TI + t;                      // TJ >= TI
  int wr = wv >> 1, wc = wv & 1;
  const bool diag = (TI == TJ);
  if (diag && wr > wc) {                // dead sub-tile: fully below diagonal
    if (threadIdx.x == 0) pd[p] = 0.f;
    return;
  }

  const u16*   Xb  = Xbf + (size_t)b * N_DIM * P_DIM;
  const float* sqb = sq + b * N_DIM;

  const int lane = threadIdx.x;         // 64 threads = 1 wave
  const int rowA = TI * 128 + wr * 64;
  const int rowB = TJ * 128 + wc * 64;
  const bool same = (rowA == rowB);     // diag (0,0)/(1,1): B tile == A tile

  // Staging geometry: per step a wave moves A (and B) 64 rows x 32 K (4 KB
  // each) = 4 loads/matrix: load q covers rows [16q,16q+16). Lane l: row
  // lr=l>>2 (+16q), 16B slot ls=l&3 -> 16 x 64B monotone segments per instr.
  const int lr = lane >> 2, ls = lane & 3;
  const u16* gA = Xb + (size_t)(rowA + lr) * P_DIM + ls * 8;
  const u16* gB = Xb + (size_t)(rowB + lr) * P_DIM + ls * 8;
  // LDS XOR swizzle: 16B chunk (row, slot s) at byte pos (s ^ ((row>>1)&3))*16.
  // ((lr+16q)>>1)&3 == (lr>>1)&3 -> write offset = base + q*1024 (immediate).
  const int wbyte = lr * 64 + ((ls ^ ((lr >> 1) & 3)) << 4);
  // Read: frag row = m*16 + h, h=lane&15; ((m*16+h)>>1)&3 == (h>>1)&3
  // -> read offset = base + m*1024 (immediate).
  const int h = lane & 15, ks = lane >> 4;
  const int rbyte = h * 64 + (((ks ^ ((h >> 1) & 3))) << 4);

  uint4 a0, a1, a2, a3, b0, b1, b2, b3;   // named: never an array (R7 lesson)

#define LOAD_A(k0) do {                                            \
    a0 = *(const uint4*)(gA + (k0));                               \
    a1 = *(const uint4*)(gA + 4096 + (k0));                        \
    a2 = *(const uint4*)(gA + 8192 + (k0));                        \
    a3 = *(const uint4*)(gA + 12288 + (k0));                       \
  } while (0)
#define LOAD_B(k0) do {                                            \
    if (!same) {                                                   \
      b0 = *(const uint4*)(gB + (k0));                             \
      b1 = *(const uint4*)(gB + 4096 + (k0));                      \
      b2 = *(const uint4*)(gB + 8192 + (k0));                      \
      b3 = *(const uint4*)(gB + 12288 + (k0));                     \
    }                                                              \
  } while (0)
#define WRITE_T(buf) do {                                          \
    char* wa = (char*)&lds[buf][0][0] + wbyte;                     \
    *(uint4*)(wa)        = a0;                                     \
    *(uint4*)(wa + 1024) = a1;                                     \
    *(uint4*)(wa + 2048) = a2;                                     \
    *(uint4*)(wa + 3072) = a3;                                     \
    if (!same) {                                                   \
      char* wb = (char*)&lds[buf][1][0] + wbyte;                   \
      *(uint4*)(wb)        = b0;                                   \
      *(uint4*)(wb + 1024) = b1;                                   \
      *(uint4*)(wb + 2048) = b2;                                   \
      *(uint4*)(wb + 3072) = b3;                                   \
    }                                                              \
  } while (0)

  f32x4 acc[4][4];
  #pragma unroll
  for (int m = 0; m < 4; ++m)
    #pragma unroll
    for (int n = 0; n < 4; ++n)
      acc[m][n] = (f32x4)(0.f);

  // Prologue: fill buffer 0.
  LOAD_A(0); LOAD_B(0);
  WRITE_T(0);

  #pragma unroll
  for (int k = 0; k < 8; ++k) {
    const int buf = k & 1;
    if (k < 7) { LOAD_A((k + 1) * BK); LOAD_B((k + 1) * BK); }  // fly under MFMA
    {
      const char* Ab = (const char*)&lds[buf][0][0] + rbyte;
      const char* Bb = same ? Ab : ((const char*)&lds[buf][1][0] + rbyte);
      bf16x8 af0 = *(const bf16x8*)(Ab);
      bf16x8 af1 = *(const bf16x8*)(Ab + 1024);
      bf16x8 af2 = *(const bf16x8*)(Ab + 2048);
      bf16x8 af3 = *(const bf16x8*)(Ab + 3072);
      bf16x8 bf0 = *(const bf16x8*)(Bb);
      bf16x8 bf1 = *(const bf16x8*)(Bb + 1024);
      bf16x8 bf2 = *(const bf16x8*)(Bb + 2048);
      bf16x8 bf3 = *(const bf16x8*)(Bb + 3072);
      acc[0][0] = __builtin_amdgcn_mfma_f32_16x16x32_bf16(af0, bf0, acc[0][0], 0, 0, 0);
      acc[0][1] = __builtin_amdgcn_mfma_f32_16x16x32_bf16(af0, bf1, acc[0][1], 0, 0, 0);
      acc[0][2] = __builtin_amdgcn_mfma_f32_16x16x32_bf16(af0, bf2, acc[0][2], 0, 0, 0);
      acc[0][3] = __builtin_amdgcn_mfma_f32_16x16x32_bf16(af0, bf3, acc[0][3], 0, 0, 0);
      acc[1][0] = __builtin_amdgcn_mfma_f32_16x16x32_bf16(af1, bf0, acc[1][0], 0, 0, 0);
      acc[1][1] = __builtin_amdgcn_mfma_f32_16x16x32_bf16(af1, bf1, acc[1][1], 0, 0, 0);
      acc[1][2] = __builtin_amdgcn_mfma_f32_16x16x32_bf16(af1, bf2, acc[1][2], 0, 0, 0);
      acc[1][3] = __builtin_amdgcn_mfma_f32_16x16x32_bf16(af1, bf3, acc[1][3], 0, 0, 0);
      acc[2][0] = __builtin_amdgcn_mfma_f32_16x16x32_bf16(af2, bf0, acc[2][0], 0, 0, 0);
      acc[2][1] = __builtin_amdgcn_mfma_f32_16x16x32_bf16(af2, bf1, acc[2][1], 0, 0, 0);
      acc[2][2] = __builtin_amdgcn_mfma_f32_16x16x32_bf16(af2, bf2, acc[2][2], 0, 0, 0);
      acc[2][3] = __builtin_amdgcn_mfma_f32_16x16x32_bf16(af2, bf3, acc[2][3], 0, 0, 0);
      acc[3][0] = __builtin_amdgcn_mfma_f32_16x16x32_bf16(af3, bf0, acc[3][0], 0, 0, 0);
      acc[3][1] = __builtin_amdgcn_mfma_f32_16x16x32_bf16(af3, bf1, acc[3][1], 0, 0, 0);
      acc[3][2] = __builtin_amdgcn_mfma_f32_16x16x32_bf16(af3, bf2, acc[3][2], 0, 0, 0);
      acc[3][3] = __builtin_amdgcn_mfma_f32_16x16x32_bf16(af3, bf3, acc[3][3], 0, 0, 0);
    }
    if (k < 7) WRITE_T(buf ^ 1);   // other buffer; wave-local ordering only
  }
#undef LOAD_A
#undef LOAD_B
#undef WRITE_T

  // Epilogue: C layout (m89/m91): col = lane&15, row = (lane>>4)*4 + v.
  float sqa[16], sqc[4];
  {
    int rb2 = rowA + (lane >> 4) * 4;
    int cb  = rowB + (lane & 15);
    #pragma unroll
    for (int m = 0; m < 4; ++m)
      #pragma unroll
      for (int v = 0; v < 4; ++v)
        sqa[m * 4 + v] = sqb[rb2 + m * 16 + v];
    #pragma unroll
    for (int n = 0; n < 4; ++n)
      sqc[n] = sqb[cb + n * 16];
  }
  float ssum = 0.f;
  #pragma unroll
  for (int m = 0; m < 4; ++m) {
    #pragma unroll
    for (int n = 0; n < 4; ++n) {
      #pragma unroll
      for (int v = 0; v < 4; ++v) {
        float d2 = sqa[m * 4 + v] + sqc[n] - 2.f * acc[m][n][v];
        float d  = sqrtf(fmaxf(d2, 0.f));
        if (same) {
          int li = m * 16 + (lane >> 4) * 4 + v;   // local row
          int lj = n * 16 + (lane & 15);           // local col
          d = (li < lj) ? d : 0.f;
        }
        ssum += d;
      }
    }
  }
  #pragma unroll
  for (int off = 32; off; off >>= 1) ssum += __shfl_down(ssum, off);
  if (lane == 0) pd[p] = ssum;
}

// ---------------------------------------------------------------------------
// Kernel 3: reduce partials (double) and combine.
// ---------------------------------------------------------------------------
__global__ __launch_bounds__(256) void finalize_kernel(
    const float* __restrict__ pb, const float* __restrict__ pd,
    float* __restrict__ out) {
  int tid = threadIdx.x;
  double s = 0.0, d = 0.0;
  for (int i = tid; i < NB_PREP; i += 256) s += (double)pb[i];
  for (int i = tid; i < NB_GRAM; i += 256) d += (double)pd[i];
  #pragma unroll
  for (int off = 32; off; off >>= 1) {
    s += __shfl_down(s, off);
    d += __shfl_down(d, off);
  }
  __shared__ double sb[4], db[4];
  int w = tid >> 6, lane = tid & 63;
  if (lane == 0) { sb[w] = s; db[w] = d; }
  __syncthreads();
  if (tid == 0) {
    double bce = (sb[0] + sb[1] + sb[2] + sb[3]) /
                 (double)((size_t)B_DIM * N_DIM * P_DIM);
    double reg = (db[0] + db[1] + db[2] + db[3]) / (double)N_DIM;
    out[0] = (float)(bce - reg);
  }
}

extern "C" void kernel_launch(void* const* d_in, const int* in_sizes, int n_in,
                              void* d_out, int out_size, void* d_ws, size_t ws_size,
                              hipStream_t stream) {
  const float* X = (const float*)d_in[0];
  const float* T = (const float*)d_in[1];
  float* out = (float*)d_out;

  // ws layout:
  //   [0, 64KB)        pb  — per-block BCE partials (16384 f32)
  //   [64KB, 100KB)    pd  — per-wave dist partials (9216 f32)
  //   [112KB, 368KB)   sq  — per-row sum of squares (65536 f32)
  //   [384KB, ~34MB)   Xbf — bf16 copy of X
  float* pb  = (float*)d_ws;
  float* pd  = (float*)((char*)d_ws + (64 << 10));
  float* sq  = (float*)((char*)d_ws + (112 << 10));
  u16*   Xbf = (u16*)  ((char*)d_ws + (384 << 10));

  prep_kernel<<<NB_PREP, 256, 0, stream>>>(X, T, Xbf, sq, pb);
  gram_kernel<<<NB_GRAM, 64, 0, stream>>>(Xbf, sq, pd);
  finalize_kernel<<<1, 256, 0, stream>>>(pb, pd, out);
}